// Round 3
// baseline (284.704 us; speedup 1.0000x reference)
//
#include <hip/hip_runtime.h>

// Reaction-diffusion (vegetation NCA) single Euler step, fused.
// w' = w + (lap(w) - 0.2 w + 1.845 - U) * 1e-4,  U = w*b*(1+3b)
// b' = b + (0.05 lap(b) - 0.3 T b + 0.449 U) * 1e-4
// Laplacian: 5-point, replicate (edge) padding.
//
// R2 redesign: baseline (1 row/block, VGPR=24) was latency-bound -- compiler
// serialized the loads into ~6 dependent round-trips per wave (all pipes at
// 5-20%, HBM 21%). Now: 4 rows/thread with 16 independent upfront float4
// loads (forced MLP, ~16KB in flight per wave), horizontal halo via shfl,
// nontemporal streaming stores.

namespace {
constexpr int IMGS = 16;
constexpr int H = 1024;
constexpr int W = 1024;
constexpr size_t PLANE = (size_t)H * W;
constexpr int RPB = 4;                              // rows per block/thread
}

typedef float f4 __attribute__((ext_vector_type(4)));

__global__ __launch_bounds__(256) void nca_step(
    const float* __restrict__ wg, const float* __restrict__ bg,
    const float* __restrict__ Tg, float* __restrict__ owg,
    float* __restrict__ obg)
{
    // XCD-aware swizzle: grid = 4096 = 8 * 512, bijective. Each XCD gets a
    // contiguous band (2 whole images) so vertical halo rows are L2-local.
    const int nwg = gridDim.x;
    const int cpx = nwg >> 3;
    const int bid = blockIdx.x;
    const int swz = (bid & 7) * cpx + (bid >> 3);

    const int img = swz >> 8;                       // 256 row-tiles per image
    const int r0  = (swz & 255) * RPB;
    const int t    = threadIdx.x;
    const int lane = t & 63;
    const int x0   = t << 2;                        // 4 floats per thread

    const float* wp = wg + (size_t)img * PLANE;
    const float* bp = bg + (size_t)img * PLANE;
    const float* Tp = Tg + (size_t)img * PLANE;

    const int rm1 = (r0 > 0)       ? r0 - 1   : 0;  // replicate padding
    const int rp4 = (r0 + RPB < H) ? r0 + RPB : H - 1;

    // ---- 16 independent loads, all issued before any use (MLP) ----
    f4 wv[RPB + 2], bv[RPB + 2], Tv[RPB];
    wv[0] = *(const f4*)(wp + (size_t)rm1 * W + x0);
    bv[0] = *(const f4*)(bp + (size_t)rm1 * W + x0);
#pragma unroll
    for (int i = 0; i < RPB; ++i) {
        wv[i + 1] = *(const f4*)(wp + (size_t)(r0 + i) * W + x0);
        bv[i + 1] = *(const f4*)(bp + (size_t)(r0 + i) * W + x0);
        Tv[i] = __builtin_nontemporal_load((const f4*)(Tp + (size_t)(r0 + i) * W + x0));
    }
    wv[RPB + 1] = *(const f4*)(wp + (size_t)rp4 * W + x0);
    bv[RPB + 1] = *(const f4*)(bp + (size_t)rp4 * W + x0);

#pragma unroll
    for (int i = 0; i < RPB; ++i) {
        const f4 cw = wv[i + 1], uw = wv[i], dw = wv[i + 2];
        const f4 cb = bv[i + 1], ub = bv[i], db = bv[i + 2];
        const f4 cT = Tv[i];

        // Horizontal neighbors: in-wave via shfl; wave-edge lanes (0/63) fix
        // up with a predicated scalar load (L1 hit) or edge-replicate.
        float wl = __shfl_up(cw.w, 1);
        float wr = __shfl_down(cw.x, 1);
        float bl = __shfl_up(cb.w, 1);
        float br = __shfl_down(cb.x, 1);
        const float* wrow = wp + (size_t)(r0 + i) * W;
        const float* brow = bp + (size_t)(r0 + i) * W;
        if (lane == 0) {
            wl = (x0 > 0) ? wrow[x0 - 1] : cw.x;
            bl = (x0 > 0) ? brow[x0 - 1] : cb.x;
        }
        if (lane == 63) {
            wr = (x0 + 4 < W) ? wrow[x0 + 4] : cw.w;
            br = (x0 + 4 < W) ? brow[x0 + 4] : cb.w;
        }

        // 5-point Laplacians -- same summation order as the (bit-exact)
        // baseline: up + down + left + right - 4*center.
        f4 lw, lb;
        lw.x = uw.x + dw.x + wl   + cw.y - 4.0f * cw.x;
        lw.y = uw.y + dw.y + cw.x + cw.z - 4.0f * cw.y;
        lw.z = uw.z + dw.z + cw.y + cw.w - 4.0f * cw.z;
        lw.w = uw.w + dw.w + cw.z + wr   - 4.0f * cw.w;

        lb.x = ub.x + db.x + bl   + cb.y - 4.0f * cb.x;
        lb.y = ub.y + db.y + cb.x + cb.z - 4.0f * cb.y;
        lb.z = ub.z + db.z + cb.y + cb.w - 4.0f * cb.z;
        lb.w = ub.w + db.w + cb.z + br   - 4.0f * cb.w;

        f4 ow4, ob4;
#pragma unroll
        for (int j = 0; j < 4; ++j) {
            const float up = cw[j] * cb[j] * (1.0f + 3.0f * cb[j]);
            ow4[j] = cw[j] + (lw[j] - 0.2f * cw[j] + 1.845f - up) * 1e-4f;
            ob4[j] = cb[j] + (0.05f * lb[j] - 0.3f * cT[j] * cb[j] + 0.449f * up) * 1e-4f;
        }

        const size_t oidx = (size_t)img * PLANE + (size_t)(r0 + i) * W + x0;
        __builtin_nontemporal_store(ow4, (f4*)(owg + oidx));
        __builtin_nontemporal_store(ob4, (f4*)(obg + oidx));
    }
}

extern "C" void kernel_launch(void* const* d_in, const int* in_sizes, int n_in,
                              void* d_out, int out_size, void* d_ws, size_t ws_size,
                              hipStream_t stream) {
    const float* w = (const float*)d_in[0];
    const float* b = (const float*)d_in[1];
    const float* T = (const float*)d_in[2];
    float* ow = (float*)d_out;                      // w_new first (return order)
    float* ob = ow + (size_t)IMGS * PLANE;          // then b_new

    dim3 grid(IMGS * (H / RPB));                    // 4096 blocks, 4 rows each
    dim3 block(W / 4);                              // 256 threads x float4
    nca_step<<<grid, block, 0, stream>>>(w, b, T, ow, ob);
}

// Round 4
// 283.796 us; speedup vs baseline: 1.0032x; 1.0032x over previous
//
#include <hip/hip_runtime.h>

// Reaction-diffusion (vegetation NCA) single Euler step, fused.
// w' = w + (lap(w) - 0.2 w + 1.845 - U) * 1e-4,  U = w*b*(1+3b)
// b' = b + (0.05 lap(b) - 0.3 T b + 0.449 U) * 1e-4
// Laplacian: 5-point, replicate (edge) padding.
//
// R3: R2 (4 rows/thread) improved 135->105us but VGPR=40 proved the compiler
// sank the 16 upfront loads to their uses (serial chains again; HBM 28%,
// VALU 6.7%). This round: ALL loads (16x float4 + predicated edge scalars)
// issued in a prologue, then sched_barrier(0) pins the load/compute boundary
// so ~16KB/wave stays in flight. Arithmetic identical (absmax==0 so far).

namespace {
constexpr int IMGS = 16;
constexpr int H = 1024;
constexpr int W = 1024;
constexpr size_t PLANE = (size_t)H * W;
constexpr int RPB = 4;                              // rows per block/thread
}

typedef float f4 __attribute__((ext_vector_type(4)));

__global__ __launch_bounds__(256) void nca_step(
    const float* __restrict__ wg, const float* __restrict__ bg,
    const float* __restrict__ Tg, float* __restrict__ owg,
    float* __restrict__ obg)
{
    // XCD-aware swizzle: grid = 4096 = 8 * 512, bijective. Each XCD gets a
    // contiguous band (2 whole images) so vertical halo rows are L2-local.
    const int nwg = gridDim.x;
    const int cpx = nwg >> 3;
    const int bid = blockIdx.x;
    const int swz = (bid & 7) * cpx + (bid >> 3);

    const int img = swz >> 8;                       // 256 row-tiles per image
    const int r0  = (swz & 255) * RPB;
    const int t    = threadIdx.x;
    const int lane = t & 63;
    const int x0   = t << 2;                        // 4 floats per thread

    const float* wp = wg + (size_t)img * PLANE;
    const float* bp = bg + (size_t)img * PLANE;
    const float* Tp = Tg + (size_t)img * PLANE;

    const int rm1 = (r0 > 0)       ? r0 - 1   : 0;  // replicate padding
    const int rp4 = (r0 + RPB < H) ? r0 + RPB : H - 1;

    // ---- prologue: issue EVERYTHING before any use ----
    f4 wv[RPB + 2], bv[RPB + 2], Tv[RPB];
    wv[0] = *(const f4*)(wp + (size_t)rm1 * W + x0);
    bv[0] = *(const f4*)(bp + (size_t)rm1 * W + x0);
    wv[RPB + 1] = *(const f4*)(wp + (size_t)rp4 * W + x0);
    bv[RPB + 1] = *(const f4*)(bp + (size_t)rp4 * W + x0);
#pragma unroll
    for (int i = 0; i < RPB; ++i) {
        wv[i + 1] = *(const f4*)(wp + (size_t)(r0 + i) * W + x0);
        bv[i + 1] = *(const f4*)(bp + (size_t)(r0 + i) * W + x0);
        Tv[i] = __builtin_nontemporal_load((const f4*)(Tp + (size_t)(r0 + i) * W + x0));
    }

    // Edge fixups, hoisted & predicated (6 active threads/block; L1 hits).
    const bool needL = (lane == 0)  && (x0 > 0);
    const bool needR = (lane == 63) && (x0 + 4 < W);
    float wlf[RPB], blf[RPB], wrf[RPB], brf[RPB];
#pragma unroll
    for (int i = 0; i < RPB; ++i) {
        const float* wrow = wp + (size_t)(r0 + i) * W;
        const float* brow = bp + (size_t)(r0 + i) * W;
        wlf[i] = needL ? wrow[x0 - 1] : 0.0f;
        blf[i] = needL ? brow[x0 - 1] : 0.0f;
        wrf[i] = needR ? wrow[x0 + 4] : 0.0f;
        brf[i] = needR ? brow[x0 + 4] : 0.0f;
    }

    // Pin the load/compute boundary: nothing above sinks below this point.
    __builtin_amdgcn_sched_barrier(0);

#pragma unroll
    for (int i = 0; i < RPB; ++i) {
        const f4 cw = wv[i + 1], uw = wv[i], dw = wv[i + 2];
        const f4 cb = bv[i + 1], ub = bv[i], db = bv[i + 2];
        const f4 cT = Tv[i];

        // Horizontal neighbors: in-wave via shfl; wave-edge lanes use the
        // prefetched fixup (or edge-replicate at the image border).
        float wl = __shfl_up(cw.w, 1);
        float wr = __shfl_down(cw.x, 1);
        float bl = __shfl_up(cb.w, 1);
        float br = __shfl_down(cb.x, 1);
        if (lane == 0) {
            wl = (x0 > 0) ? wlf[i] : cw.x;
            bl = (x0 > 0) ? blf[i] : cb.x;
        }
        if (lane == 63) {
            wr = (x0 + 4 < W) ? wrf[i] : cw.w;
            br = (x0 + 4 < W) ? brf[i] : cb.w;
        }

        // 5-point Laplacians -- same summation order as the (bit-exact)
        // baseline: up + down + left + right - 4*center.
        f4 lw, lb;
        lw.x = uw.x + dw.x + wl   + cw.y - 4.0f * cw.x;
        lw.y = uw.y + dw.y + cw.x + cw.z - 4.0f * cw.y;
        lw.z = uw.z + dw.z + cw.y + cw.w - 4.0f * cw.z;
        lw.w = uw.w + dw.w + cw.z + wr   - 4.0f * cw.w;

        lb.x = ub.x + db.x + bl   + cb.y - 4.0f * cb.x;
        lb.y = ub.y + db.y + cb.x + cb.z - 4.0f * cb.y;
        lb.z = ub.z + db.z + cb.y + cb.w - 4.0f * cb.z;
        lb.w = ub.w + db.w + cb.z + br   - 4.0f * cb.w;

        f4 ow4, ob4;
#pragma unroll
        for (int j = 0; j < 4; ++j) {
            const float up = cw[j] * cb[j] * (1.0f + 3.0f * cb[j]);
            ow4[j] = cw[j] + (lw[j] - 0.2f * cw[j] + 1.845f - up) * 1e-4f;
            ob4[j] = cb[j] + (0.05f * lb[j] - 0.3f * cT[j] * cb[j] + 0.449f * up) * 1e-4f;
        }

        const size_t oidx = (size_t)img * PLANE + (size_t)(r0 + i) * W + x0;
        __builtin_nontemporal_store(ow4, (f4*)(owg + oidx));
        __builtin_nontemporal_store(ob4, (f4*)(obg + oidx));
    }
}

extern "C" void kernel_launch(void* const* d_in, const int* in_sizes, int n_in,
                              void* d_out, int out_size, void* d_ws, size_t ws_size,
                              hipStream_t stream) {
    const float* w = (const float*)d_in[0];
    const float* b = (const float*)d_in[1];
    const float* T = (const float*)d_in[2];
    float* ow = (float*)d_out;                      // w_new first (return order)
    float* ob = ow + (size_t)IMGS * PLANE;          // then b_new

    dim3 grid(IMGS * (H / RPB));                    // 4096 blocks, 4 rows each
    dim3 block(W / 4);                              // 256 threads x float4
    nca_step<<<grid, block, 0, stream>>>(w, b, T, ow, ob);
}